// Round 13
// baseline (907.357 us; speedup 1.0000x reference)
//
#include <hip/hip_runtime.h>
#include <hip/hip_bf16.h>

#define HW_  9216        // 96*96
#define CHW_ 2359296     // 256*9216

typedef __attribute__((ext_vector_type(8))) short bf16x8;
typedef __attribute__((ext_vector_type(4))) float f32x4;
typedef __attribute__((ext_vector_type(2))) float f32x2;

__device__ __forceinline__ short f2bf(float f) {
  union { float f; unsigned u; } v; v.f = f;
  unsigned r = v.u + 0x7fff + ((v.u >> 16) & 1);   // RNE, no NaNs in this data
  return (short)(r >> 16);
}
__device__ __forceinline__ float bflo(unsigned u) {
  union { unsigned u; float f; } v; v.u = u << 16; return v.f;
}
__device__ __forceinline__ float bfhi(unsigned u) {
  union { unsigned u; float f; } v; v.u = u & 0xffff0000u; return v.f;
}
__device__ __forceinline__ short bfc(float f) {
  __hip_bfloat16 h = __float2bfloat16(f);           // RNE
  union { __hip_bfloat16 h; short s; } u; u.h = h; return u.s;
}
// bilinear combine of one packed channel-pair across 4 corners (pk-f32 math)
__device__ __forceinline__ unsigned cmb2(unsigned u0, unsigned u1,
                                         unsigned u2, unsigned u3,
                                         const float4 w) {
  f32x2 c0 = {bflo(u0), bfhi(u0)};
  f32x2 c1 = {bflo(u1), bfhi(u1)};
  f32x2 c2 = {bflo(u2), bfhi(u2)};
  f32x2 c3 = {bflo(u3), bfhi(u3)};
  f32x2 s = c0 * w.x;
  s = s + c1 * w.y;
  s = s + c2 * w.z;
  s = s + c3 * w.w;
  union { short2 p; unsigned u; } r;
  r.p.x = bfc(s.x); r.p.y = bfc(s.y);
  return r.u;
}
__device__ __forceinline__ bf16x8 combine4(const uint4 g0, const uint4 g1,
                                           const uint4 g2, const uint4 g3,
                                           const float4 w) {
  union { bf16x8 v; unsigned u[4]; } r;
  r.u[0] = cmb2(g0.x, g1.x, g2.x, g3.x, w);
  r.u[1] = cmb2(g0.y, g1.y, g2.y, g3.y, w);
  r.u[2] = cmb2(g0.z, g1.z, g2.z, g3.z, w);
  r.u[3] = cmb2(g0.w, g1.w, g2.w, g3.w, w);
  return r.v;
}

// ---------------- x: NCHW f32 -> NHWC bf16 ----------------
__global__ void k_transpose2(const float* __restrict__ x, short* __restrict__ xt) {
  __shared__ float tile[32][33];
  const int b = blockIdx.z;
  const int hw0 = blockIdx.x * 32;
  const int c0 = blockIdx.y * 32;
  const int tx = threadIdx.x, ty = threadIdx.y;   // 32 x 8
  const float* xb = x + (size_t)b * CHW_;
  short* xtb = xt + (size_t)b * CHW_;
#pragma unroll
  for (int s = 0; s < 4; ++s)
    tile[ty + s * 8][tx] = xb[(size_t)(c0 + ty + s * 8) * HW_ + hw0 + tx];
  __syncthreads();
  const int tid = ty * 32 + tx;
  const int cp = tid & 15;
  const int hh = tid >> 4;
#pragma unroll
  for (int s = 0; s < 2; ++s) {
    const int hw = hh + s * 16;
    short2 v;
    v.x = f2bf(tile[2 * cp][hw]);
    v.y = f2bf(tile[2 * cp + 1][hw]);
    *(short2*)&xtb[(size_t)(hw0 + hw) * 256 + c0 + 2 * cp] = v;
  }
}

// ------- prep: deform_w + offset_w -> bf16 MFMA b-fragment layouts -------
__global__ void k_prep(const float* __restrict__ dw, const float* __restrict__ ow,
                       short* __restrict__ wfrag, short* __restrict__ owfrag) {
  const int idx = blockIdx.x * 256 + threadIdx.x;
  if (idx < 589824) {
    const int i = idx & 7, l = (idx >> 3) & 63, nf = (idx >> 9) & 15, kb = idx >> 13;
    const int o = nf * 16 + (l & 15);
    const int c = (kb & 7) * 32 + (l >> 4) * 8 + i;
    const int kk = kb >> 3;
    wfrag[idx] = f2bf(dw[(size_t)(o * 256 + c) * 9 + kk]);
  } else {
    const int j = idx - 589824;   // < 73728
    const int i = j & 7, l = (j >> 3) & 63, nf = (j >> 9) & 1, s = j >> 10;
    const int o = nf * 16 + (l & 15);
    const int c = ((s & 7) << 5) + ((l >> 4) << 3) + i;
    const int kk = s >> 3;
    owfrag[j] = (o < 18) ? f2bf(ow[(size_t)(o * 256 + c) * 9 + kk]) : (short)0;
  }
}

// ---- fused: offset conv (A) + metadata (B) + M-split deform GEMM (C) ----
// 1152 blocks x 128 threads (2 waves). Block = 1 ho row x 32 wo, all 256 outs.
// Phase C: M-split — wave w owns pixels [w*16, w*16+16) x ALL 256 outputs.
// A: per-lane register gathers + combine (no LDS). B: 32KB K64 slice staged
// into LDS once per step (reg-staged 1 step ahead), read by BOTH waves.
__global__ __launch_bounds__(128) void k_deform(
    const short* __restrict__ xt, const short* __restrict__ wfrag,
    const short* __restrict__ owfrag, const float* __restrict__ ob,
    const float* __restrict__ db, float* __restrict__ out) {
  __shared__ __align__(16) char smem[39680];
  short*  bufB = (short*)smem;               // [16384] shorts = 32KB B slice
  float*  offsLDS = (float*)smem;            // [32][32] f32 overlay (phase A out)
  float4* mwP = (float4*)(smem + 32768);     // [288]
  short4* miP = (short4*)(smem + 37376);     // [288]

  const int tid = threadIdx.x;
  const int blk0 = blockIdx.x;
  const int blk = (blk0 & 7) * 144 + (blk0 >> 3);   // bijective XCD swizzle
  const int b = blk / 288;
  const int r = blk % 288;
  const int ho0 = r / 3;
  const int wo0 = (r % 3) * 32;
  const short* xb = xt + (size_t)b * CHW_;
  const int lane = tid & 63;
  const int wave = tid >> 6;   // 0..1

  // ---- phase A: offset conv for this block's 32 pixels (register MFMA) ----
  {
    const int pA = wave * 16 + (lane & 15);
    const int woA = wo0 + pA;
    const int coff = (lane >> 4) << 3;
    f32x4 oa0 = {0.f, 0.f, 0.f, 0.f}, oa1 = {0.f, 0.f, 0.f, 0.f};
#pragma unroll 4
    for (int s = 0; s < 72; ++s) {
      const int kk = s >> 3;
      const int c0 = (s & 7) << 5;
      const int y = ho0 - 1 + kk / 3;
      const int x = woA - 1 + kk % 3;
      bf16x8 af = {0, 0, 0, 0, 0, 0, 0, 0};
      if ((unsigned)y < 96u && (unsigned)x < 96u)
        af = *(const bf16x8*)(xb + ((y * 96 + x) << 8) + c0 + coff);
      const bf16x8 b0 = *(const bf16x8*)(owfrag + (size_t)s * 1024 + lane * 8);
      const bf16x8 b1 = *(const bf16x8*)(owfrag + (size_t)s * 1024 + 512 + lane * 8);
      oa0 = __builtin_amdgcn_mfma_f32_16x16x32_bf16(af, b0, oa0, 0, 0, 0);
      oa1 = __builtin_amdgcn_mfma_f32_16x16x32_bf16(af, b1, oa1, 0, 0, 0);
    }
    const int r0 = wave * 16 + (lane >> 4) * 4;
    const int cc = lane & 15;
#pragma unroll
    for (int j = 0; j < 4; ++j) {
      offsLDS[(r0 + j) * 32 + cc] = oa0[j];
      offsLDS[(r0 + j) * 32 + 16 + cc] = oa1[j];
    }
  }
  __syncthreads();

  // ---- phase B: sampling metadata: 9 kk x 32 pixels ----
  for (int u = tid; u < 288; u += 128) {
    const int kk = u >> 5;
    const int p = u & 31;
    const int wo = wo0 + p;
    const float dy = offsLDS[p * 32 + 2 * kk] + ob[2 * kk];
    const float dx = offsLDS[p * 32 + 2 * kk + 1] + ob[2 * kk + 1];
    const float py = (float)(ho0 - 1 + kk / 3) + dy;
    const float px = (float)(wo - 1 + kk % 3) + dx;
    const float y0f = floorf(py), x0f = floorf(px);
    const float ty = py - y0f, tx = px - x0f;
    const int y0 = (int)y0f, x0 = (int)x0f;
    const int y1 = y0 + 1, x1 = x0 + 1;
    const float vy0 = ((unsigned)y0 < 96u) ? 1.f : 0.f;
    const float vy1 = ((unsigned)y1 < 96u) ? 1.f : 0.f;
    const float vx0 = ((unsigned)x0 < 96u) ? 1.f : 0.f;
    const float vx1 = ((unsigned)x1 < 96u) ? 1.f : 0.f;
    const float oy = 1.f - ty, ox = 1.f - tx;
    float4 w4;
    w4.x = oy * ox * vy0 * vx0;
    w4.y = oy * tx * vy0 * vx1;
    w4.z = ty * ox * vy1 * vx0;
    w4.w = ty * tx * vy1 * vx1;
    const int cy0 = min(max(y0, 0), 95), cy1 = min(max(y1, 0), 95);
    const int cx0 = min(max(x0, 0), 95), cx1 = min(max(x1, 0), 95);
    mwP[u] = w4;
    miP[u] = make_short4((short)(cy0 * 96 + cx0), (short)(cy0 * 96 + cx1),
                         (short)(cy1 * 96 + cx0), (short)(cy1 * 96 + cx1));
  }
  __syncthreads();   // offsLDS dead from here; bufB region free

  // ---- phase C: M-split, K-step = 64, B via LDS (shared by both waves) ----
  const int p0 = lane & 15;
  const int myp = wave * 16 + p0;      // my pixel (A row)
  const int kc8 = (lane >> 4) << 3;    // channel sub-chunk within 32

  f32x4 acc[16];
#pragma unroll
  for (int j = 0; j < 16; ++j) acc[j] = (f32x4){0.f, 0.f, 0.f, 0.f};

  // metadata for kk(0)=0
  float4 w4 = mwP[myp];
  int4 a4;
  {
    const short4 m0 = miP[myp];
    a4.x = ((int)m0.x) << 8; a4.y = ((int)m0.y) << 8;
    a4.z = ((int)m0.z) << 8; a4.w = ((int)m0.w) << 8;
  }

  // prologue: gathers for sb=0; stage B(0); combine -> af
  uint4 G[2][4];
#pragma unroll
  for (int ks = 0; ks < 2; ++ks) {
    const int cl = ks * 32 + kc8;
    G[ks][0] = *(const uint4*)(xb + a4.x + cl);
    G[ks][1] = *(const uint4*)(xb + a4.y + cl);
    G[ks][2] = *(const uint4*)(xb + a4.z + cl);
    G[ks][3] = *(const uint4*)(xb + a4.w + cl);
  }
  uint4 breg[16];
#pragma unroll
  for (int i = 0; i < 16; ++i)
    breg[i] = *(const uint4*)(wfrag + i * 1024 + tid * 8);
#pragma unroll
  for (int i = 0; i < 16; ++i)
    *(uint4*)(bufB + i * 1024 + tid * 8) = breg[i];
  bf16x8 afA = combine4(G[0][0], G[0][1], G[0][2], G[0][3], w4);
  bf16x8 afB = combine4(G[1][0], G[1][1], G[1][2], G[1][3], w4);
  __syncthreads();

  for (int sb = 0; sb < 36; ++sb) {
    const int sbn = sb + 1;
    // refresh metadata to kk(sbn); issue gathers + B loads for sbn
    if (sb < 35) {
      if ((sbn & 3) == 0) {
        const int kkn = sbn >> 2;
        w4 = mwP[kkn * 32 + myp];
        const short4 mn = miP[kkn * 32 + myp];
        a4.x = ((int)mn.x) << 8; a4.y = ((int)mn.y) << 8;
        a4.z = ((int)mn.z) << 8; a4.w = ((int)mn.w) << 8;
      }
      const int cb = ((sbn & 3) << 6) + kc8;
#pragma unroll
      for (int ks = 0; ks < 2; ++ks) {
        const int cl = cb + ks * 32;
        G[ks][0] = *(const uint4*)(xb + a4.x + cl);
        G[ks][1] = *(const uint4*)(xb + a4.y + cl);
        G[ks][2] = *(const uint4*)(xb + a4.z + cl);
        G[ks][3] = *(const uint4*)(xb + a4.w + cl);
      }
      const short* wsl = wfrag + (size_t)sbn * 16384;
#pragma unroll
      for (int i = 0; i < 16; ++i)
        breg[i] = *(const uint4*)(wsl + i * 1024 + tid * 8);
    }

    // MFMAs: 2 ks x 16 n-frags, B from LDS (both waves read same data)
#pragma unroll
    for (int j = 0; j < 16; ++j) {
      const bf16x8 bf = *(const bf16x8*)(bufB + j * 512 + lane * 8);
      acc[j] = __builtin_amdgcn_mfma_f32_16x16x32_bf16(afA, bf, acc[j], 0, 0, 0);
    }
#pragma unroll
    for (int j = 0; j < 16; ++j) {
      const bf16x8 bf = *(const bf16x8*)(bufB + 8192 + j * 512 + lane * 8);
      acc[j] = __builtin_amdgcn_mfma_f32_16x16x32_bf16(afB, bf, acc[j], 0, 0, 0);
    }

    // combine next A-fragments (gathers had the MFMA block of slack)
    if (sb < 35) {
      afA = combine4(G[0][0], G[0][1], G[0][2], G[0][3], w4);
      afB = combine4(G[1][0], G[1][1], G[1][2], G[1][3], w4);
      __syncthreads();   // all LDS reads of bufB done
#pragma unroll
      for (int i = 0; i < 16; ++i)
        *(uint4*)(bufB + i * 1024 + tid * 8) = breg[i];
      __syncthreads();   // writes visible
    }
  }

  // ---- epilogue: acc[j] regs = 4 consecutive pixels -> float4 stores ----
  const int col = lane & 15;
  const int rg = lane >> 4;
  const int pixbase = ho0 * 96 + wo0 + wave * 16 + rg * 4;
#pragma unroll
  for (int j = 0; j < 16; ++j) {
    const int o = j * 16 + col;
    const float bv = db[o];
    float4 v;
    v.x = acc[j][0] + bv;
    v.y = acc[j][1] + bv;
    v.z = acc[j][2] + bv;
    v.w = acc[j][3] + bv;
    *(float4*)(out + (size_t)(b * 256 + o) * HW_ + pixbase) = v;
  }
}

extern "C" void kernel_launch(void* const* d_in, const int* in_sizes, int n_in,
                              void* d_out, int out_size, void* d_ws, size_t ws_size,
                              hipStream_t stream) {
  const float* x  = (const float*)d_in[0];
  const float* ow = (const float*)d_in[1];
  const float* ob = (const float*)d_in[2];
  const float* dw = (const float*)d_in[3];
  const float* db = (const float*)d_in[4];
  float* out = (float*)d_out;
  float* ws = (float*)d_ws;

  short* xt     = (short*)ws;                // 9,437,184 bf16 (18.9 MB)
  short* wfrag  = (short*)(ws + 4718592);    //   589,824 bf16
  short* owfrag = wfrag + 589824;            //    73,728 bf16  (~20.2 MB total)

  hipLaunchKernelGGL(k_transpose2, dim3(288, 8, 4), dim3(32, 8, 1), 0, stream, x, xt);
  hipLaunchKernelGGL(k_prep, dim3(2592), dim3(256), 0, stream, dw, ow, wfrag, owfrag);
  hipLaunchKernelGGL(k_deform, dim3(1152), dim3(128), 0, stream,
                     xt, wfrag, owfrag, ob, db, out);
}

// Round 14
// 167.936 us; speedup vs baseline: 5.4030x; 5.4030x over previous
//
#include <hip/hip_runtime.h>
#include <hip/hip_bf16.h>

#define HW_  9216        // 96*96
#define CHW_ 2359296     // 256*9216
#define VST  76          // LDS A-tile row stride (shorts): 64ch + 12 pad

typedef __attribute__((ext_vector_type(8))) short bf16x8;
typedef __attribute__((ext_vector_type(4))) float f32x4;
typedef __attribute__((ext_vector_type(2))) float f32x2;

__device__ __forceinline__ short f2bf(float f) {
  union { float f; unsigned u; } v; v.f = f;
  unsigned r = v.u + 0x7fff + ((v.u >> 16) & 1);   // RNE, no NaNs in this data
  return (short)(r >> 16);
}
__device__ __forceinline__ float bflo(unsigned u) {
  union { unsigned u; float f; } v; v.u = u << 16; return v.f;
}
__device__ __forceinline__ float bfhi(unsigned u) {
  union { unsigned u; float f; } v; v.u = u & 0xffff0000u; return v.f;
}
__device__ __forceinline__ short bfc(float f) {
  __hip_bfloat16 h = __float2bfloat16(f);           // RNE
  union { __hip_bfloat16 h; short s; } u; u.h = h; return u.s;
}
// bilinear combine of one packed channel-pair across 4 corners (pk-f32 math)
__device__ __forceinline__ unsigned cmb2(unsigned u0, unsigned u1,
                                         unsigned u2, unsigned u3,
                                         const float4 w) {
  f32x2 c0 = {bflo(u0), bfhi(u0)};
  f32x2 c1 = {bflo(u1), bfhi(u1)};
  f32x2 c2 = {bflo(u2), bfhi(u2)};
  f32x2 c3 = {bflo(u3), bfhi(u3)};
  f32x2 s = c0 * w.x;
  s = s + c1 * w.y;
  s = s + c2 * w.z;
  s = s + c3 * w.w;
  union { short2 p; unsigned u; } r;
  r.p.x = bfc(s.x); r.p.y = bfc(s.y);
  return r.u;
}
__device__ __forceinline__ bf16x8 combine4(const uint4 g0, const uint4 g1,
                                           const uint4 g2, const uint4 g3,
                                           const float4 w) {
  union { bf16x8 v; unsigned u[4]; } r;
  r.u[0] = cmb2(g0.x, g1.x, g2.x, g3.x, w);
  r.u[1] = cmb2(g0.y, g1.y, g2.y, g3.y, w);
  r.u[2] = cmb2(g0.z, g1.z, g2.z, g3.z, w);
  r.u[3] = cmb2(g0.w, g1.w, g2.w, g3.w, w);
  return r.v;
}

// ---------------- x: NCHW f32 -> NHWC bf16 ----------------
__global__ void k_transpose2(const float* __restrict__ x, short* __restrict__ xt) {
  __shared__ float tile[32][33];
  const int b = blockIdx.z;
  const int hw0 = blockIdx.x * 32;
  const int c0 = blockIdx.y * 32;
  const int tx = threadIdx.x, ty = threadIdx.y;   // 32 x 8
  const float* xb = x + (size_t)b * CHW_;
  short* xtb = xt + (size_t)b * CHW_;
#pragma unroll
  for (int s = 0; s < 4; ++s)
    tile[ty + s * 8][tx] = xb[(size_t)(c0 + ty + s * 8) * HW_ + hw0 + tx];
  __syncthreads();
  const int tid = ty * 32 + tx;
  const int cp = tid & 15;
  const int hh = tid >> 4;
#pragma unroll
  for (int s = 0; s < 2; ++s) {
    const int hw = hh + s * 16;
    short2 v;
    v.x = f2bf(tile[2 * cp][hw]);
    v.y = f2bf(tile[2 * cp + 1][hw]);
    *(short2*)&xtb[(size_t)(hw0 + hw) * 256 + c0 + 2 * cp] = v;
  }
}

// ------- prep: deform_w + offset_w -> bf16 MFMA b-fragment layouts -------
__global__ void k_prep(const float* __restrict__ dw, const float* __restrict__ ow,
                       short* __restrict__ wfrag, short* __restrict__ owfrag) {
  const int idx = blockIdx.x * 256 + threadIdx.x;
  if (idx < 589824) {
    const int i = idx & 7, l = (idx >> 3) & 63, nf = (idx >> 9) & 15, kb = idx >> 13;
    const int o = nf * 16 + (l & 15);
    const int c = (kb & 7) * 32 + (l >> 4) * 8 + i;
    const int kk = kb >> 3;
    wfrag[idx] = f2bf(dw[(size_t)(o * 256 + c) * 9 + kk]);
  } else {
    const int j = idx - 589824;   // < 73728
    const int i = j & 7, l = (j >> 3) & 63, nf = (j >> 9) & 1, s = j >> 10;
    const int o = nf * 16 + (l & 15);
    const int c = ((s & 7) << 5) + ((l >> 4) << 3) + i;
    const int kk = s >> 3;
    owfrag[j] = (o < 18) ? f2bf(ow[(size_t)(o * 256 + c) * 9 + kk]) : (short)0;
  }
}

// ---- fused: offset conv (A) + metadata (B) + deform GEMM (C, K-step=64) ----
// 1152 blocks x 256 threads (4 waves). Block = 1 ho row x 32 wo, all 256 outs.
// Phase C: waves split N (wave w: 32 px x outputs [w*64, w*64+64)).
// A staged in LDS (64 ch/step, dbuf, 1 barrier/step; 8 ch/thread staging);
// B-fragments straight from L2 (8 loads/wave/step). No register prefetch
// arrays (R13 lesson: they spill).
__global__ __launch_bounds__(256) void k_deform(
    const short* __restrict__ xt, const short* __restrict__ wfrag,
    const short* __restrict__ owfrag, const float* __restrict__ ob,
    const float* __restrict__ db, float* __restrict__ out) {
  __shared__ __align__(16) char smem[16640];
  short*  vals = (short*)smem;               // 2 x [32][VST] bf16 (dbuf)
  float*  offsLDS = (float*)smem;            // [32][32] f32 overlay (phase A out)
  float4* mwP = (float4*)(smem + 9728);      // [288]
  short4* miP = (short4*)(smem + 14336);     // [288]

  const int tid = threadIdx.x;
  const int blk0 = blockIdx.x;
  const int blk = (blk0 & 7) * 144 + (blk0 >> 3);   // bijective XCD swizzle
  const int b = blk / 288;
  const int r = blk % 288;
  const int ho0 = r / 3;
  const int wo0 = (r % 3) * 32;
  const short* xb = xt + (size_t)b * CHW_;
  const int lane = tid & 63;
  const int wave = tid >> 6;   // 0..3

  // ---- phase A: offset conv, 2x2 wave split (pixel-half x output-frag) ----
  {
    const int wmA = wave & 1;       // pixel half
    const int wnA = wave >> 1;      // output frag (0: o0-15, 1: o16-31)
    const int pA = wmA * 16 + (lane & 15);
    const int woA = wo0 + pA;
    const int coff = (lane >> 4) << 3;
    f32x4 oa = {0.f, 0.f, 0.f, 0.f};
#pragma unroll 4
    for (int s = 0; s < 72; ++s) {
      const int kk = s >> 3;
      const int c0 = (s & 7) << 5;
      const int y = ho0 - 1 + kk / 3;
      const int x = woA - 1 + kk % 3;
      bf16x8 af = {0, 0, 0, 0, 0, 0, 0, 0};
      if ((unsigned)y < 96u && (unsigned)x < 96u)
        af = *(const bf16x8*)(xb + ((y * 96 + x) << 8) + c0 + coff);
      const bf16x8 bo = *(const bf16x8*)(owfrag + (size_t)s * 1024 + wnA * 512 + lane * 8);
      oa = __builtin_amdgcn_mfma_f32_16x16x32_bf16(af, bo, oa, 0, 0, 0);
    }
    const int r0 = wmA * 16 + (lane >> 4) * 4;
    const int cc = lane & 15;
#pragma unroll
    for (int j = 0; j < 4; ++j)
      offsLDS[(r0 + j) * 32 + wnA * 16 + cc] = oa[j];
  }
  __syncthreads();

  // ---- phase B: sampling metadata: 9 kk x 32 pixels ----
  for (int u = tid; u < 288; u += 256) {
    const int kk = u >> 5;
    const int p = u & 31;
    const int wo = wo0 + p;
    const float dy = offsLDS[p * 32 + 2 * kk] + ob[2 * kk];
    const float dx = offsLDS[p * 32 + 2 * kk + 1] + ob[2 * kk + 1];
    const float py = (float)(ho0 - 1 + kk / 3) + dy;
    const float px = (float)(wo - 1 + kk % 3) + dx;
    const float y0f = floorf(py), x0f = floorf(px);
    const float ty = py - y0f, tx = px - x0f;
    const int y0 = (int)y0f, x0 = (int)x0f;
    const int y1 = y0 + 1, x1 = x0 + 1;
    const float vy0 = ((unsigned)y0 < 96u) ? 1.f : 0.f;
    const float vy1 = ((unsigned)y1 < 96u) ? 1.f : 0.f;
    const float vx0 = ((unsigned)x0 < 96u) ? 1.f : 0.f;
    const float vx1 = ((unsigned)x1 < 96u) ? 1.f : 0.f;
    const float oy = 1.f - ty, ox = 1.f - tx;
    float4 w4;
    w4.x = oy * ox * vy0 * vx0;
    w4.y = oy * tx * vy0 * vx1;
    w4.z = ty * ox * vy1 * vx0;
    w4.w = ty * tx * vy1 * vx1;
    const int cy0 = min(max(y0, 0), 95), cy1 = min(max(y1, 0), 95);
    const int cx0 = min(max(x0, 0), 95), cx1 = min(max(x1, 0), 95);
    mwP[u] = w4;
    miP[u] = make_short4((short)(cy0 * 96 + cx0), (short)(cy0 * 96 + cx1),
                         (short)(cy1 * 96 + cx0), (short)(cy1 * 96 + cx1));
  }
  __syncthreads();

  // ---- phase C: K-step = 64 channels, double-buffered, 1 barrier/step ----
  const int px = tid >> 3;        // 0..31 (staging pixel)
  const int ch0 = (tid & 7) << 3; // 8-channel slab base

  f32x4 acc[2][4];
#pragma unroll
  for (int m = 0; m < 2; ++m)
#pragma unroll
    for (int j = 0; j < 4; ++j) acc[m][j] = (f32x4){0.f, 0.f, 0.f, 0.f};

  // staging metadata registers (refreshed when sb % 4 == 0)
  float4 w4 = mwP[px];
  int4 a4;
  {
    const short4 m0 = miP[px];
    a4.x = ((int)m0.x) << 8; a4.y = ((int)m0.y) << 8;
    a4.z = ((int)m0.z) << 8; a4.w = ((int)m0.w) << 8;
  }

  // prologue: stage sb=0 (channels 0..63) into buf0 (1 combine/thread)
  {
    const uint4 g0 = *(const uint4*)(xb + a4.x + ch0);
    const uint4 g1 = *(const uint4*)(xb + a4.y + ch0);
    const uint4 g2 = *(const uint4*)(xb + a4.z + ch0);
    const uint4 g3 = *(const uint4*)(xb + a4.w + ch0);
    *(bf16x8*)(&vals[px * VST + ch0]) = combine4(g0, g1, g2, g3, w4);
  }
  __syncthreads();

  for (int sb = 0; sb < 36; ++sb) {
    const short* vcur = vals + (sb & 1) * (32 * VST);
    short* vnxt = vals + ((sb & 1) ^ 1) * (32 * VST);
    const int kb0 = 2 * sb;

    // B-fragments: 2 k-subs x 4 n-frags for this wave (L2, 16B/lane)
    bf16x8 bfr[2][4];
    {
      const size_t wb0 = ((size_t)(kb0 * 16 + wave * 4) * 64 + lane) * 8;
      const size_t wb1 = wb0 + (size_t)16 * 64 * 8;
#pragma unroll
      for (int j = 0; j < 4; ++j) bfr[0][j] = *(const bf16x8*)(wfrag + wb0 + (size_t)j * 512);
#pragma unroll
      for (int j = 0; j < 4; ++j) bfr[1][j] = *(const bf16x8*)(wfrag + wb1 + (size_t)j * 512);
    }

    // issue gathers for sb+1 early (covered by the 16 MFMAs below)
    uint4 G0, G1, G2, G3;
    float4 w4n = w4;
    int4 a4n = a4;
    if (sb < 35) {
      const int sbn = sb + 1;
      if ((sbn & 3) == 0) {
        const int kkn = sbn >> 2;
        w4n = mwP[kkn * 32 + px];
        const short4 mn = miP[kkn * 32 + px];
        a4n.x = ((int)mn.x) << 8; a4n.y = ((int)mn.y) << 8;
        a4n.z = ((int)mn.z) << 8; a4n.w = ((int)mn.w) << 8;
      }
      const int cl = ((sbn & 3) << 6) + ch0;
      G0 = *(const uint4*)(xb + a4n.x + cl);
      G1 = *(const uint4*)(xb + a4n.y + cl);
      G2 = *(const uint4*)(xb + a4n.z + cl);
      G3 = *(const uint4*)(xb + a4n.w + cl);
    }

    // MFMAs on current buffer: 2 k-subs x 2 m-frags x 4 n-frags
#pragma unroll
    for (int ks = 0; ks < 2; ++ks) {
#pragma unroll
      for (int mf = 0; mf < 2; ++mf) {
        const int row = mf * 16 + (lane & 15);
        const bf16x8 af = *(const bf16x8*)(&vcur[row * VST + ks * 32 + ((lane >> 4) << 3)]);
#pragma unroll
        for (int j = 0; j < 4; ++j)
          acc[mf][j] = __builtin_amdgcn_mfma_f32_16x16x32_bf16(af, bfr[ks][j], acc[mf][j], 0, 0, 0);
      }
    }

    // combine + write next buffer
    if (sb < 35) {
      *(bf16x8*)(&vnxt[px * VST + ch0]) = combine4(G0, G1, G2, G3, w4n);
      w4 = w4n; a4 = a4n;
    }
    __syncthreads();
  }

  // ---- epilogue: D regs = 4 consecutive pixels -> float4 stores ----
  const int col = lane & 15;
  const int rg = lane >> 4;
#pragma unroll
  for (int mf = 0; mf < 2; ++mf) {
    const int pix = mf * 16 + rg * 4;
#pragma unroll
    for (int j = 0; j < 4; ++j) {
      const int o = wave * 64 + j * 16 + col;
      const float bv = db[o];
      float4 v;
      v.x = acc[mf][j][0] + bv;
      v.y = acc[mf][j][1] + bv;
      v.z = acc[mf][j][2] + bv;
      v.w = acc[mf][j][3] + bv;
      *(float4*)(out + (size_t)(b * 256 + o) * HW_ + ho0 * 96 + wo0 + pix) = v;
    }
  }
}

extern "C" void kernel_launch(void* const* d_in, const int* in_sizes, int n_in,
                              void* d_out, int out_size, void* d_ws, size_t ws_size,
                              hipStream_t stream) {
  const float* x  = (const float*)d_in[0];
  const float* ow = (const float*)d_in[1];
  const float* ob = (const float*)d_in[2];
  const float* dw = (const float*)d_in[3];
  const float* db = (const float*)d_in[4];
  float* out = (float*)d_out;
  float* ws = (float*)d_ws;

  short* xt     = (short*)ws;                // 9,437,184 bf16 (18.9 MB)
  short* wfrag  = (short*)(ws + 4718592);    //   589,824 bf16
  short* owfrag = wfrag + 589824;            //    73,728 bf16  (~20.2 MB total)

  hipLaunchKernelGGL(k_transpose2, dim3(288, 8, 4), dim3(32, 8, 1), 0, stream, x, xt);
  hipLaunchKernelGGL(k_prep, dim3(2592), dim3(256), 0, stream, dw, ow, wfrag, owfrag);
  hipLaunchKernelGGL(k_deform, dim3(1152), dim3(256), 0, stream,
                     xt, wfrag, owfrag, ob, db, out);
}

// Round 15
// 160.472 us; speedup vs baseline: 5.6543x; 1.0465x over previous
//
#include <hip/hip_runtime.h>
#include <hip/hip_bf16.h>

#define HW_  9216        // 96*96
#define CHW_ 2359296     // 256*9216
#define VST  76          // LDS A-tile row stride (shorts): 64ch + 12 pad

typedef __attribute__((ext_vector_type(8))) short bf16x8;
typedef __attribute__((ext_vector_type(4))) float f32x4;
typedef __attribute__((ext_vector_type(2))) float f32x2;

__device__ __forceinline__ short f2bf(float f) {
  union { float f; unsigned u; } v; v.f = f;
  unsigned r = v.u + 0x7fff + ((v.u >> 16) & 1);   // RNE, no NaNs in this data
  return (short)(r >> 16);
}
__device__ __forceinline__ float bflo(unsigned u) {
  union { unsigned u; float f; } v; v.u = u << 16; return v.f;
}
__device__ __forceinline__ float bfhi(unsigned u) {
  union { unsigned u; float f; } v; v.u = u & 0xffff0000u; return v.f;
}
__device__ __forceinline__ short bfc(float f) {
  __hip_bfloat16 h = __float2bfloat16(f);           // RNE
  union { __hip_bfloat16 h; short s; } u; u.h = h; return u.s;
}
// bilinear combine of one packed channel-pair across 4 corners (pk-f32 math)
__device__ __forceinline__ unsigned cmb2(unsigned u0, unsigned u1,
                                         unsigned u2, unsigned u3,
                                         const float4 w) {
  f32x2 c0 = {bflo(u0), bfhi(u0)};
  f32x2 c1 = {bflo(u1), bfhi(u1)};
  f32x2 c2 = {bflo(u2), bfhi(u2)};
  f32x2 c3 = {bflo(u3), bfhi(u3)};
  f32x2 s = c0 * w.x;
  s = s + c1 * w.y;
  s = s + c2 * w.z;
  s = s + c3 * w.w;
  union { short2 p; unsigned u; } r;
  r.p.x = bfc(s.x); r.p.y = bfc(s.y);
  return r.u;
}
__device__ __forceinline__ bf16x8 combine4(const uint4 g0, const uint4 g1,
                                           const uint4 g2, const uint4 g3,
                                           const float4 w) {
  union { bf16x8 v; unsigned u[4]; } r;
  r.u[0] = cmb2(g0.x, g1.x, g2.x, g3.x, w);
  r.u[1] = cmb2(g0.y, g1.y, g2.y, g3.y, w);
  r.u[2] = cmb2(g0.z, g1.z, g2.z, g3.z, w);
  r.u[3] = cmb2(g0.w, g1.w, g2.w, g3.w, w);
  return r.v;
}

// ---------------- x: NCHW f32 -> NHWC bf16 ----------------
__global__ void k_transpose2(const float* __restrict__ x, short* __restrict__ xt) {
  __shared__ float tile[32][33];
  const int b = blockIdx.z;
  const int hw0 = blockIdx.x * 32;
  const int c0 = blockIdx.y * 32;
  const int tx = threadIdx.x, ty = threadIdx.y;   // 32 x 8
  const float* xb = x + (size_t)b * CHW_;
  short* xtb = xt + (size_t)b * CHW_;
#pragma unroll
  for (int s = 0; s < 4; ++s)
    tile[ty + s * 8][tx] = xb[(size_t)(c0 + ty + s * 8) * HW_ + hw0 + tx];
  __syncthreads();
  const int tid = ty * 32 + tx;
  const int cp = tid & 15;
  const int hh = tid >> 4;
#pragma unroll
  for (int s = 0; s < 2; ++s) {
    const int hw = hh + s * 16;
    short2 v;
    v.x = f2bf(tile[2 * cp][hw]);
    v.y = f2bf(tile[2 * cp + 1][hw]);
    *(short2*)&xtb[(size_t)(hw0 + hw) * 256 + c0 + 2 * cp] = v;
  }
}

// ------- prep: deform_w + offset_w -> bf16 MFMA b-fragment layouts -------
__global__ void k_prep(const float* __restrict__ dw, const float* __restrict__ ow,
                       short* __restrict__ wfrag, short* __restrict__ owfrag) {
  const int idx = blockIdx.x * 256 + threadIdx.x;
  if (idx < 589824) {
    const int i = idx & 7, l = (idx >> 3) & 63, nf = (idx >> 9) & 15, kb = idx >> 13;
    const int o = nf * 16 + (l & 15);
    const int c = (kb & 7) * 32 + (l >> 4) * 8 + i;
    const int kk = kb >> 3;
    wfrag[idx] = f2bf(dw[(size_t)(o * 256 + c) * 9 + kk]);
  } else {
    const int j = idx - 589824;   // < 73728
    const int i = j & 7, l = (j >> 3) & 63, nf = (j >> 9) & 1, s = j >> 10;
    const int o = nf * 16 + (l & 15);
    const int c = ((s & 7) << 5) + ((l >> 4) << 3) + i;
    const int kk = s >> 3;
    owfrag[j] = (o < 18) ? f2bf(ow[(size_t)(o * 256 + c) * 9 + kk]) : (short)0;
  }
}

// ---- fused: offset conv (A) + metadata (B) + deform GEMM (C, K-step=64) ----
// 1152 blocks x 128 threads (2 waves). Block = 1 ho row x 32 wo, all 256 outs.
// Phase C (champion R11 + T4/T14/T5): gathers for tile t+2 issued at bottom
// of step t and carried ACROSS a raw lgkmcnt-only barrier (no vmcnt drain);
// B-frags loaded at step top (in-step); setprio around MFMA cluster.
__global__ __launch_bounds__(128) void k_deform(
    const short* __restrict__ xt, const short* __restrict__ wfrag,
    const short* __restrict__ owfrag, const float* __restrict__ ob,
    const float* __restrict__ db, float* __restrict__ out) {
  __shared__ __align__(16) char smem[16640];
  short*  vals = (short*)smem;               // 2 x [32][VST] bf16 (dbuf)
  float*  offsLDS = (float*)smem;            // [32][32] f32 overlay (phase A out)
  float4* mwP = (float4*)(smem + 9728);      // [288]
  short4* miP = (short4*)(smem + 14336);     // [288]

  const int tid = threadIdx.x;
  const int blk0 = blockIdx.x;
  const int blk = (blk0 & 7) * 144 + (blk0 >> 3);   // bijective XCD swizzle
  const int b = blk / 288;
  const int r = blk % 288;
  const int ho0 = r / 3;
  const int wo0 = (r % 3) * 32;
  const short* xb = xt + (size_t)b * CHW_;
  const int lane = tid & 63;
  const int wave = tid >> 6;   // 0..1

  // ---- phase A: offset conv for this block's 32 pixels (register MFMA) ----
  {
    const int pA = wave * 16 + (lane & 15);
    const int woA = wo0 + pA;
    const int coff = (lane >> 4) << 3;
    f32x4 oa0 = {0.f, 0.f, 0.f, 0.f}, oa1 = {0.f, 0.f, 0.f, 0.f};
#pragma unroll 4
    for (int s = 0; s < 72; ++s) {
      const int kk = s >> 3;
      const int c0 = (s & 7) << 5;
      const int y = ho0 - 1 + kk / 3;
      const int x = woA - 1 + kk % 3;
      bf16x8 af = {0, 0, 0, 0, 0, 0, 0, 0};
      if ((unsigned)y < 96u && (unsigned)x < 96u)
        af = *(const bf16x8*)(xb + ((y * 96 + x) << 8) + c0 + coff);
      const bf16x8 b0 = *(const bf16x8*)(owfrag + (size_t)s * 1024 + lane * 8);
      const bf16x8 b1 = *(const bf16x8*)(owfrag + (size_t)s * 1024 + 512 + lane * 8);
      oa0 = __builtin_amdgcn_mfma_f32_16x16x32_bf16(af, b0, oa0, 0, 0, 0);
      oa1 = __builtin_amdgcn_mfma_f32_16x16x32_bf16(af, b1, oa1, 0, 0, 0);
    }
    const int r0 = wave * 16 + (lane >> 4) * 4;
    const int cc = lane & 15;
#pragma unroll
    for (int j = 0; j < 4; ++j) {
      offsLDS[(r0 + j) * 32 + cc] = oa0[j];
      offsLDS[(r0 + j) * 32 + 16 + cc] = oa1[j];
    }
  }
  __syncthreads();

  // ---- phase B: sampling metadata: 9 kk x 32 pixels ----
  for (int u = tid; u < 288; u += 128) {
    const int kk = u >> 5;
    const int p = u & 31;
    const int wo = wo0 + p;
    const float dy = offsLDS[p * 32 + 2 * kk] + ob[2 * kk];
    const float dx = offsLDS[p * 32 + 2 * kk + 1] + ob[2 * kk + 1];
    const float py = (float)(ho0 - 1 + kk / 3) + dy;
    const float px = (float)(wo - 1 + kk % 3) + dx;
    const float y0f = floorf(py), x0f = floorf(px);
    const float ty = py - y0f, tx = px - x0f;
    const int y0 = (int)y0f, x0 = (int)x0f;
    const int y1 = y0 + 1, x1 = x0 + 1;
    const float vy0 = ((unsigned)y0 < 96u) ? 1.f : 0.f;
    const float vy1 = ((unsigned)y1 < 96u) ? 1.f : 0.f;
    const float vx0 = ((unsigned)x0 < 96u) ? 1.f : 0.f;
    const float vx1 = ((unsigned)x1 < 96u) ? 1.f : 0.f;
    const float oy = 1.f - ty, ox = 1.f - tx;
    float4 w4;
    w4.x = oy * ox * vy0 * vx0;
    w4.y = oy * tx * vy0 * vx1;
    w4.z = ty * ox * vy1 * vx0;
    w4.w = ty * tx * vy1 * vx1;
    const int cy0 = min(max(y0, 0), 95), cy1 = min(max(y1, 0), 95);
    const int cx0 = min(max(x0, 0), 95), cx1 = min(max(x1, 0), 95);
    mwP[u] = w4;
    miP[u] = make_short4((short)(cy0 * 96 + cx0), (short)(cy0 * 96 + cx1),
                         (short)(cy1 * 96 + cx0), (short)(cy1 * 96 + cx1));
  }
  __syncthreads();

  // ---- phase C: K-step = 64, A dbuf, gathers pipelined across raw barrier ----
  const int px = tid >> 2;        // 0..31 (staging pixel)
  const int ch0 = (tid & 3) << 4; // 16-channel group base

  f32x4 acc[2][8];
#pragma unroll
  for (int m = 0; m < 2; ++m)
#pragma unroll
    for (int j = 0; j < 8; ++j) acc[m][j] = (f32x4){0.f, 0.f, 0.f, 0.f};

  // meta registers for the PENDING gather tile (refreshed on kk boundary)
  float4 w4c = mwP[px];
  int4 a4c;
  {
    const short4 m0 = miP[px];
    a4c.x = ((int)m0.x) << 8; a4c.y = ((int)m0.y) << 8;
    a4c.z = ((int)m0.z) << 8; a4c.w = ((int)m0.w) << 8;
  }

  // prologue: stage tile 0 into buf0; issue gathers for tile 1 (kk=0)
#pragma unroll
  for (int t = 0; t < 2; ++t) {
    const int cl = ch0 + t * 8;
    const uint4 g0 = *(const uint4*)(xb + a4c.x + cl);
    const uint4 g1 = *(const uint4*)(xb + a4c.y + cl);
    const uint4 g2 = *(const uint4*)(xb + a4c.z + cl);
    const uint4 g3 = *(const uint4*)(xb + a4c.w + cl);
    *(bf16x8*)(&vals[px * VST + cl]) = combine4(g0, g1, g2, g3, w4c);
  }
  uint4 G[2][4];
#pragma unroll
  for (int t = 0; t < 2; ++t) {
    const int cl = 64 + ch0 + t * 8;   // tile 1: (1&3)<<6 = 64
    G[t][0] = *(const uint4*)(xb + a4c.x + cl);
    G[t][1] = *(const uint4*)(xb + a4c.y + cl);
    G[t][2] = *(const uint4*)(xb + a4c.z + cl);
    G[t][3] = *(const uint4*)(xb + a4c.w + cl);
  }
  asm volatile("s_waitcnt lgkmcnt(0)" ::: "memory");
  __builtin_amdgcn_s_barrier();
  __builtin_amdgcn_sched_barrier(0);

  for (int sb = 0; sb < 36; ++sb) {
    const short* vcur = vals + (sb & 1) * (32 * VST);
    short* vnxt = vals + ((sb & 1) ^ 1) * (32 * VST);
    const int kb0 = 2 * sb;

    // B-fragments for this step (L2, in-step consumption)
    bf16x8 bfr[2][8];
    {
      const size_t wb0 = ((size_t)(kb0 * 16 + wave * 8) * 64 + lane) * 8;
      const size_t wb1 = wb0 + (size_t)16 * 64 * 8;
#pragma unroll
      for (int j = 0; j < 8; ++j) bfr[0][j] = *(const bf16x8*)(wfrag + wb0 + (size_t)j * 512);
#pragma unroll
      for (int j = 0; j < 8; ++j) bfr[1][j] = *(const bf16x8*)(wfrag + wb1 + (size_t)j * 512);
    }

    // MFMAs on current buffer: 2 k-subs x 2 m-frags x 8 n-frags
    __builtin_amdgcn_s_setprio(1);
#pragma unroll
    for (int ks = 0; ks < 2; ++ks) {
#pragma unroll
      for (int mf = 0; mf < 2; ++mf) {
        const int row = mf * 16 + (lane & 15);
        const bf16x8 af = *(const bf16x8*)(&vcur[row * VST + ks * 32 + ((lane >> 4) << 3)]);
#pragma unroll
        for (int j = 0; j < 8; ++j)
          acc[mf][j] = __builtin_amdgcn_mfma_f32_16x16x32_bf16(af, bfr[ks][j], acc[mf][j], 0, 0, 0);
      }
    }
    __builtin_amdgcn_s_setprio(0);

    // combine pending gathers (issued last step, arrived long ago) -> tile sb+1
    if (sb < 35) {
#pragma unroll
      for (int t = 0; t < 2; ++t)
        *(bf16x8*)(&vnxt[px * VST + ch0 + t * 8]) =
            combine4(G[t][0], G[t][1], G[t][2], G[t][3], w4c);
    }

    // refresh meta + issue gathers for tile sb+2 (will cross the barrier)
    if (sb < 34) {
      const int tn = sb + 2;
      if ((tn & 3) == 0) {
        const int kkn = tn >> 2;
        w4c = mwP[kkn * 32 + px];
        const short4 mn = miP[kkn * 32 + px];
        a4c.x = ((int)mn.x) << 8; a4c.y = ((int)mn.y) << 8;
        a4c.z = ((int)mn.z) << 8; a4c.w = ((int)mn.w) << 8;
      }
      const int cb = ((tn & 3) << 6) + ch0;
#pragma unroll
      for (int t = 0; t < 2; ++t) {
        const int cl = cb + t * 8;
        G[t][0] = *(const uint4*)(xb + a4c.x + cl);
        G[t][1] = *(const uint4*)(xb + a4c.y + cl);
        G[t][2] = *(const uint4*)(xb + a4c.z + cl);
        G[t][3] = *(const uint4*)(xb + a4c.w + cl);
      }
    }

    // raw barrier: drain LDS only — gathers stay in flight across it
    if (sb < 35) {
      asm volatile("s_waitcnt lgkmcnt(0)" ::: "memory");
      __builtin_amdgcn_s_barrier();
      __builtin_amdgcn_sched_barrier(0);
    }
  }

  // ---- epilogue: D regs = 4 consecutive pixels -> float4 stores ----
  const int col = lane & 15;
  const int rg = lane >> 4;
#pragma unroll
  for (int mf = 0; mf < 2; ++mf) {
    const int pix = mf * 16 + rg * 4;
#pragma unroll
    for (int j = 0; j < 8; ++j) {
      const int o = wave * 128 + j * 16 + col;
      const float bv = db[o];
      float4 v;
      v.x = acc[mf][j][0] + bv;
      v.y = acc[mf][j][1] + bv;
      v.z = acc[mf][j][2] + bv;
      v.w = acc[mf][j][3] + bv;
      *(float4*)(out + (size_t)(b * 256 + o) * HW_ + ho0 * 96 + wo0 + pix) = v;
    }
  }
}

extern "C" void kernel_launch(void* const* d_in, const int* in_sizes, int n_in,
                              void* d_out, int out_size, void* d_ws, size_t ws_size,
                              hipStream_t stream) {
  const float* x  = (const float*)d_in[0];
  const float* ow = (const float*)d_in[1];
  const float* ob = (const float*)d_in[2];
  const float* dw = (const float*)d_in[3];
  const float* db = (const float*)d_in[4];
  float* out = (float*)d_out;
  float* ws = (float*)d_ws;

  short* xt     = (short*)ws;                // 9,437,184 bf16 (18.9 MB)
  short* wfrag  = (short*)(ws + 4718592);    //   589,824 bf16
  short* owfrag = wfrag + 589824;            //    73,728 bf16  (~20.2 MB total)

  hipLaunchKernelGGL(k_transpose2, dim3(288, 8, 4), dim3(32, 8, 1), 0, stream, x, xt);
  hipLaunchKernelGGL(k_prep, dim3(2592), dim3(256), 0, stream, dw, ow, wfrag, owfrag);
  hipLaunchKernelGGL(k_deform, dim3(1152), dim3(128), 0, stream,
                     xt, wfrag, owfrag, ob, db, out);
}

// Round 16
// 153.921 us; speedup vs baseline: 5.8949x; 1.0426x over previous
//
#include <hip/hip_runtime.h>
#include <hip/hip_bf16.h>

#define HW_  9216        // 96*96
#define CHW_ 2359296     // 256*9216

typedef __attribute__((ext_vector_type(8))) short bf16x8;
typedef __attribute__((ext_vector_type(4))) float f32x4;

__device__ __forceinline__ short f2bf(float f) {
  union { float f; unsigned u; } v; v.f = f;
  unsigned r = v.u + 0x7fff + ((v.u >> 16) & 1);   // RNE, no NaNs in this data
  return (short)(r >> 16);
}
__device__ __forceinline__ float bflo(unsigned u) {
  union { unsigned u; float f; } v; v.u = u << 16; return v.f;
}
__device__ __forceinline__ float bfhi(unsigned u) {
  union { unsigned u; float f; } v; v.u = u & 0xffff0000u; return v.f;
}

// bilinear combine of 4 packed-bf16 corners (8 channels) -> bf16 A-fragment
__device__ __forceinline__ bf16x8 combine4(const uint4 g0, const uint4 g1,
                                           const uint4 g2, const uint4 g3,
                                           const float4 w) {
  bf16x8 r;
#define CMB(gw0, gw1, gw2, gw3, e)                                              \
  r[e]     = f2bf(w.x * bflo(gw0) + w.y * bflo(gw1) + w.z * bflo(gw2) + w.w * bflo(gw3)); \
  r[(e)+1] = f2bf(w.x * bfhi(gw0) + w.y * bfhi(gw1) + w.z * bfhi(gw2) + w.w * bfhi(gw3));
  CMB(g0.x, g1.x, g2.x, g3.x, 0)
  CMB(g0.y, g1.y, g2.y, g3.y, 2)
  CMB(g0.z, g1.z, g2.z, g3.z, 4)
  CMB(g0.w, g1.w, g2.w, g3.w, 6)
#undef CMB
  return r;
}

// ---------------- x: NCHW f32 -> NHWC bf16 ----------------
__global__ void k_transpose2(const float* __restrict__ x, short* __restrict__ xt) {
  __shared__ float tile[32][33];
  const int b = blockIdx.z;
  const int hw0 = blockIdx.x * 32;
  const int c0 = blockIdx.y * 32;
  const int tx = threadIdx.x, ty = threadIdx.y;   // 32 x 8
  const float* xb = x + (size_t)b * CHW_;
  short* xtb = xt + (size_t)b * CHW_;
#pragma unroll
  for (int s = 0; s < 4; ++s)
    tile[ty + s * 8][tx] = xb[(size_t)(c0 + ty + s * 8) * HW_ + hw0 + tx];
  __syncthreads();
  const int tid = ty * 32 + tx;
  const int cp = tid & 15;    // channel pair
  const int hh = tid >> 4;    // 0..15
#pragma unroll
  for (int s = 0; s < 2; ++s) {
    const int hw = hh + s * 16;
    short2 v;
    v.x = f2bf(tile[2 * cp][hw]);
    v.y = f2bf(tile[2 * cp + 1][hw]);
    *(short2*)&xtb[(size_t)(hw0 + hw) * 256 + c0 + 2 * cp] = v;
  }
}

// ------- prep: deform_w + offset_w -> bf16 MFMA b-fragment layouts -------
__global__ void k_prep(const float* __restrict__ dw, const float* __restrict__ ow,
                       short* __restrict__ wfrag, short* __restrict__ owfrag) {
  const int idx = blockIdx.x * 256 + threadIdx.x;
  if (idx < 589824) {
    const int i = idx & 7, l = (idx >> 3) & 63, nf = (idx >> 9) & 15, kb = idx >> 13;
    const int o = nf * 16 + (l & 15);
    const int c = (kb & 7) * 32 + (l >> 4) * 8 + i;
    const int kk = kb >> 3;
    wfrag[idx] = f2bf(dw[(size_t)(o * 256 + c) * 9 + kk]);
  } else {
    const int j = idx - 589824;   // < 73728
    const int i = j & 7, l = (j >> 3) & 63, nf = (j >> 9) & 1, s = j >> 10;
    const int o = nf * 16 + (l & 15);
    const int c = ((s & 7) << 5) + ((l >> 4) << 3) + i;
    const int kk = s >> 3;
    owfrag[j] = (o < 18) ? f2bf(ow[(size_t)(o * 256 + c) * 9 + kk]) : (short)0;
  }
}

// ---- fused: offset conv (A) + metadata (B) + deform GEMM (C, K-step=64) ----
// 1152 blocks x 128 threads (2 waves). Block = 1 ho row x 32 wo, all 256 outs.
// Phase C: waves split N (wave w: 32 px x outputs [w*128, w*128+128)).
// A staged in LDS (64 ch / step, double-buffered, 1 barrier/step);
// staging metadata register-resident, refreshed every 4th step.
// R16 = R9 champion + s_setprio(1) around the MFMA cluster (T5, zero-reg).
__global__ __launch_bounds__(128) void k_deform(
    const short* __restrict__ xt, const short* __restrict__ wfrag,
    const short* __restrict__ owfrag, const float* __restrict__ ob,
    const float* __restrict__ db, float* __restrict__ out) {
  __shared__ __align__(16) char smem[25344];
  short*  vals = (short*)smem;               // 2 x [32][72] bf16 (dbuf, 64ch+pad)
  float*  offsLDS = (float*)smem;            // [32][32] f32 overlay (phase A out)
  float4* mwP = (float4*)(smem + 18432);     // [288]
  short4* miP = (short4*)(smem + 23040);     // [288]

  const int tid = threadIdx.x;
  // XCD-aware bijective swizzle: 1152 = 8 XCDs x 144 contiguous strips
  const int blk0 = blockIdx.x;
  const int blk = (blk0 & 7) * 144 + (blk0 >> 3);
  const int b = blk / 288;
  const int r = blk % 288;
  const int ho0 = r / 3;
  const int wo0 = (r % 3) * 32;
  const short* xb = xt + (size_t)b * CHW_;
  const int lane = tid & 63;
  const int wave = tid >> 6;   // 0..1

  // ---- phase A: offset conv for this block's 32 pixels (register MFMA) ----
  {
    const int pA = wave * 16 + (lane & 15);
    const int woA = wo0 + pA;
    const int coff = (lane >> 4) << 3;
    f32x4 oa0 = {0.f, 0.f, 0.f, 0.f}, oa1 = {0.f, 0.f, 0.f, 0.f};
#pragma unroll 4
    for (int s = 0; s < 72; ++s) {
      const int kk = s >> 3;
      const int c0 = (s & 7) << 5;
      const int y = ho0 - 1 + kk / 3;
      const int x = woA - 1 + kk % 3;
      bf16x8 af = {0, 0, 0, 0, 0, 0, 0, 0};
      if ((unsigned)y < 96u && (unsigned)x < 96u)
        af = *(const bf16x8*)(xb + ((y * 96 + x) << 8) + c0 + coff);
      const bf16x8 b0 = *(const bf16x8*)(owfrag + (size_t)s * 1024 + lane * 8);
      const bf16x8 b1 = *(const bf16x8*)(owfrag + (size_t)s * 1024 + 512 + lane * 8);
      oa0 = __builtin_amdgcn_mfma_f32_16x16x32_bf16(af, b0, oa0, 0, 0, 0);
      oa1 = __builtin_amdgcn_mfma_f32_16x16x32_bf16(af, b1, oa1, 0, 0, 0);
    }
    const int r0 = wave * 16 + (lane >> 4) * 4;
    const int cc = lane & 15;
#pragma unroll
    for (int j = 0; j < 4; ++j) {
      offsLDS[(r0 + j) * 32 + cc] = oa0[j];
      offsLDS[(r0 + j) * 32 + 16 + cc] = oa1[j];
    }
  }
  __syncthreads();

  // ---- phase B: sampling metadata: 9 kk x 32 pixels ----
  for (int u = tid; u < 288; u += 128) {
    const int kk = u >> 5;
    const int p = u & 31;
    const int wo = wo0 + p;
    const float dy = offsLDS[p * 32 + 2 * kk] + ob[2 * kk];
    const float dx = offsLDS[p * 32 + 2 * kk + 1] + ob[2 * kk + 1];
    const float py = (float)(ho0 - 1 + kk / 3) + dy;
    const float px = (float)(wo - 1 + kk % 3) + dx;
    const float y0f = floorf(py), x0f = floorf(px);
    const float ty = py - y0f, tx = px - x0f;
    const int y0 = (int)y0f, x0 = (int)x0f;
    const int y1 = y0 + 1, x1 = x0 + 1;
    const float vy0 = ((unsigned)y0 < 96u) ? 1.f : 0.f;
    const float vy1 = ((unsigned)y1 < 96u) ? 1.f : 0.f;
    const float vx0 = ((unsigned)x0 < 96u) ? 1.f : 0.f;
    const float vx1 = ((unsigned)x1 < 96u) ? 1.f : 0.f;
    const float oy = 1.f - ty, ox = 1.f - tx;
    float4 w4;
    w4.x = oy * ox * vy0 * vx0;
    w4.y = oy * tx * vy0 * vx1;
    w4.z = ty * ox * vy1 * vx0;
    w4.w = ty * tx * vy1 * vx1;
    const int cy0 = min(max(y0, 0), 95), cy1 = min(max(y1, 0), 95);
    const int cx0 = min(max(x0, 0), 95), cx1 = min(max(x1, 0), 95);
    mwP[u] = w4;
    miP[u] = make_short4((short)(cy0 * 96 + cx0), (short)(cy0 * 96 + cx1),
                         (short)(cy1 * 96 + cx0), (short)(cy1 * 96 + cx1));
  }
  __syncthreads();

  // ---- phase C: K-step = 64 channels, double-buffered, 1 barrier/step ----
  const int px = tid >> 2;        // 0..31 (staging pixel)
  const int ch0 = (tid & 3) << 4; // 16-channel group base

  f32x4 acc[2][8];
#pragma unroll
  for (int m = 0; m < 2; ++m)
#pragma unroll
    for (int j = 0; j < 8; ++j) acc[m][j] = (f32x4){0.f, 0.f, 0.f, 0.f};

  // staging metadata registers (refreshed when sb % 4 == 0)
  float4 w4 = mwP[px];
  int4 a4;
  {
    const short4 m0 = miP[px];
    a4.x = ((int)m0.x) << 8; a4.y = ((int)m0.y) << 8;
    a4.z = ((int)m0.z) << 8; a4.w = ((int)m0.w) << 8;
  }

  // prologue: stage sb=0 (channels 0..63) into buf0
#pragma unroll
  for (int t = 0; t < 2; ++t) {
    const int cl = ch0 + t * 8;
    const uint4 g0 = *(const uint4*)(xb + a4.x + cl);
    const uint4 g1 = *(const uint4*)(xb + a4.y + cl);
    const uint4 g2 = *(const uint4*)(xb + a4.z + cl);
    const uint4 g3 = *(const uint4*)(xb + a4.w + cl);
    *(bf16x8*)(&vals[px * 72 + cl]) = combine4(g0, g1, g2, g3, w4);
  }
  __syncthreads();

  for (int sb = 0; sb < 36; ++sb) {
    const short* vcur = vals + (sb & 1) * 2304;
    short* vnxt = vals + ((sb & 1) ^ 1) * 2304;
    const int kb0 = 2 * sb;

    // B-fragments: 2 k-subs x 8 n-frags for this wave (L2, 16B/lane)
    bf16x8 bfr[2][8];
    {
      const size_t wb0 = ((size_t)(kb0 * 16 + wave * 8) * 64 + lane) * 8;
      const size_t wb1 = wb0 + (size_t)16 * 64 * 8;
#pragma unroll
      for (int j = 0; j < 8; ++j) bfr[0][j] = *(const bf16x8*)(wfrag + wb0 + (size_t)j * 512);
#pragma unroll
      for (int j = 0; j < 8; ++j) bfr[1][j] = *(const bf16x8*)(wfrag + wb1 + (size_t)j * 512);
    }

    // issue gathers for sb+1 early (covered by the 32 MFMAs below)
    uint4 G[2][4];
    float4 w4n = w4;
    int4 a4n = a4;
    if (sb < 35) {
      const int sbn = sb + 1;
      if ((sbn & 3) == 0) {
        const int kkn = sbn >> 2;
        w4n = mwP[kkn * 32 + px];
        const short4 mn = miP[kkn * 32 + px];
        a4n.x = ((int)mn.x) << 8; a4n.y = ((int)mn.y) << 8;
        a4n.z = ((int)mn.z) << 8; a4n.w = ((int)mn.w) << 8;
      }
      const int cb = ((sbn & 3) << 6) + ch0;
#pragma unroll
      for (int t = 0; t < 2; ++t) {
        const int cl = cb + t * 8;
        G[t][0] = *(const uint4*)(xb + a4n.x + cl);
        G[t][1] = *(const uint4*)(xb + a4n.y + cl);
        G[t][2] = *(const uint4*)(xb + a4n.z + cl);
        G[t][3] = *(const uint4*)(xb + a4n.w + cl);
      }
    }

    // MFMAs on current buffer: 2 k-subs x 2 m-frags x 8 n-frags (T5: setprio)
    __builtin_amdgcn_s_setprio(1);
#pragma unroll
    for (int ks = 0; ks < 2; ++ks) {
#pragma unroll
      for (int mf = 0; mf < 2; ++mf) {
        const int row = mf * 16 + (lane & 15);
        const bf16x8 af = *(const bf16x8*)(&vcur[row * 72 + ks * 32 + ((lane >> 4) << 3)]);
#pragma unroll
        for (int j = 0; j < 8; ++j)
          acc[mf][j] = __builtin_amdgcn_mfma_f32_16x16x32_bf16(af, bfr[ks][j], acc[mf][j], 0, 0, 0);
      }
    }
    __builtin_amdgcn_s_setprio(0);

    // combine + write next buffer
    if (sb < 35) {
      const int cb = (((sb + 1) & 3) << 6) + ch0;
#pragma unroll
      for (int t = 0; t < 2; ++t) {
        const int cl = cb + t * 8;
        *(bf16x8*)(&vnxt[px * 72 + ((cl) & 63)]) =
            combine4(G[t][0], G[t][1], G[t][2], G[t][3], w4n);
      }
      w4 = w4n; a4 = a4n;
    }
    __syncthreads();
  }

  // ---- epilogue: D regs = 4 consecutive pixels -> float4 stores ----
  const int col = lane & 15;
  const int rg = lane >> 4;
#pragma unroll
  for (int mf = 0; mf < 2; ++mf) {
    const int pix = mf * 16 + rg * 4;
#pragma unroll
    for (int j = 0; j < 8; ++j) {
      const int o = wave * 128 + j * 16 + col;
      const float bv = db[o];
      float4 v;
      v.x = acc[mf][j][0] + bv;
      v.y = acc[mf][j][1] + bv;
      v.z = acc[mf][j][2] + bv;
      v.w = acc[mf][j][3] + bv;
      *(float4*)(out + (size_t)(b * 256 + o) * HW_ + ho0 * 96 + wo0 + pix) = v;
    }
  }
}

extern "C" void kernel_launch(void* const* d_in, const int* in_sizes, int n_in,
                              void* d_out, int out_size, void* d_ws, size_t ws_size,
                              hipStream_t stream) {
  const float* x  = (const float*)d_in[0];
  const float* ow = (const float*)d_in[1];
  const float* ob = (const float*)d_in[2];
  const float* dw = (const float*)d_in[3];
  const float* db = (const float*)d_in[4];
  float* out = (float*)d_out;
  float* ws = (float*)d_ws;

  short* xt     = (short*)ws;                // 9,437,184 bf16 (18.9 MB)
  short* wfrag  = (short*)(ws + 4718592);    //   589,824 bf16
  short* owfrag = wfrag + 589824;            //    73,728 bf16  (~20.2 MB total)

  hipLaunchKernelGGL(k_transpose2, dim3(288, 8, 4), dim3(32, 8, 1), 0, stream, x, xt);
  hipLaunchKernelGGL(k_prep, dim3(2592), dim3(256), 0, stream, dw, ow, wfrag, owfrag);
  hipLaunchKernelGGL(k_deform, dim3(1152), dim3(128), 0, stream,
                     xt, wfrag, owfrag, ob, db, out);
}

// Round 17
// 130.327 us; speedup vs baseline: 6.9621x; 1.1810x over previous
//
#include <hip/hip_runtime.h>
#include <hip/hip_bf16.h>

#define HW_  9216        // 96*96
#define CHW_ 2359296     // 256*9216

typedef __attribute__((ext_vector_type(8))) short bf16x8;
typedef __attribute__((ext_vector_type(4))) float f32x4;

__device__ __forceinline__ short f2bf(float f) {
  union { float f; unsigned u; } v; v.f = f;
  unsigned r = v.u + 0x7fff + ((v.u >> 16) & 1);   // RNE, no NaNs in this data
  return (short)(r >> 16);
}
__device__ __forceinline__ float bflo(unsigned u) {
  union { unsigned u; float f; } v; v.u = u << 16; return v.f;
}
__device__ __forceinline__ float bfhi(unsigned u) {
  union { unsigned u; float f; } v; v.u = u & 0xffff0000u; return v.f;
}

// bilinear combine of 4 packed-bf16 corners (8 channels) -> bf16 A-fragment
__device__ __forceinline__ bf16x8 combine4(const uint4 g0, const uint4 g1,
                                           const uint4 g2, const uint4 g3,
                                           const float4 w) {
  bf16x8 r;
#define CMB(gw0, gw1, gw2, gw3, e)                                              \
  r[e]     = f2bf(w.x * bflo(gw0) + w.y * bflo(gw1) + w.z * bflo(gw2) + w.w * bflo(gw3)); \
  r[(e)+1] = f2bf(w.x * bfhi(gw0) + w.y * bfhi(gw1) + w.z * bfhi(gw2) + w.w * bfhi(gw3));
  CMB(g0.x, g1.x, g2.x, g3.x, 0)
  CMB(g0.y, g1.y, g2.y, g3.y, 2)
  CMB(g0.z, g1.z, g2.z, g3.z, 4)
  CMB(g0.w, g1.w, g2.w, g3.w, 6)
#undef CMB
  return r;
}

// ---------------- x: NCHW f32 -> NHWC bf16 ----------------
__global__ void k_transpose2(const float* __restrict__ x, short* __restrict__ xt) {
  __shared__ float tile[32][33];
  const int b = blockIdx.z;
  const int hw0 = blockIdx.x * 32;
  const int c0 = blockIdx.y * 32;
  const int tx = threadIdx.x, ty = threadIdx.y;   // 32 x 8
  const float* xb = x + (size_t)b * CHW_;
  short* xtb = xt + (size_t)b * CHW_;
#pragma unroll
  for (int s = 0; s < 4; ++s)
    tile[ty + s * 8][tx] = xb[(size_t)(c0 + ty + s * 8) * HW_ + hw0 + tx];
  __syncthreads();
  const int tid = ty * 32 + tx;
  const int cp = tid & 15;    // channel pair
  const int hh = tid >> 4;    // 0..15
#pragma unroll
  for (int s = 0; s < 2; ++s) {
    const int hw = hh + s * 16;
    short2 v;
    v.x = f2bf(tile[2 * cp][hw]);
    v.y = f2bf(tile[2 * cp + 1][hw]);
    *(short2*)&xtb[(size_t)(hw0 + hw) * 256 + c0 + 2 * cp] = v;
  }
}

// ------- prep: deform_w + offset_w -> bf16 MFMA b-fragment layouts -------
__global__ void k_prep(const float* __restrict__ dw, const float* __restrict__ ow,
                       short* __restrict__ wfrag, short* __restrict__ owfrag) {
  const int idx = blockIdx.x * 256 + threadIdx.x;
  if (idx < 589824) {
    const int i = idx & 7, l = (idx >> 3) & 63, nf = (idx >> 9) & 15, kb = idx >> 13;
    const int o = nf * 16 + (l & 15);
    const int c = (kb & 7) * 32 + (l >> 4) * 8 + i;
    const int kk = kb >> 3;
    wfrag[idx] = f2bf(dw[(size_t)(o * 256 + c) * 9 + kk]);
  } else {
    const int j = idx - 589824;   // < 73728
    const int i = j & 7, l = (j >> 3) & 63, nf = (j >> 9) & 1, s = j >> 10;
    const int o = nf * 16 + (l & 15);
    const int c = ((s & 7) << 5) + ((l >> 4) << 3) + i;
    const int kk = s >> 3;
    owfrag[j] = (o < 18) ? f2bf(ow[(size_t)(o * 256 + c) * 9 + kk]) : (short)0;
  }
}

// ---- fused: offset conv (A) + metadata (B) + deform GEMM (C, K-step=64) ----
// 1152 blocks x 128 threads (2 waves). Block = 1 ho row x 32 wo, all 256 outs.
// Phase C: waves split N (wave w: 32 px x outputs [w*128, w*128+128)).
// A staged in LDS (64 ch / step, double-buffered, 1 barrier/step);
// staging metadata register-resident, refreshed every 4th step.
__global__ __launch_bounds__(128) void k_deform(
    const short* __restrict__ xt, const short* __restrict__ wfrag,
    const short* __restrict__ owfrag, const float* __restrict__ ob,
    const float* __restrict__ db, float* __restrict__ out) {
  __shared__ __align__(16) char smem[25344];
  short*  vals = (short*)smem;               // 2 x [32][72] bf16 (dbuf, 64ch+pad)
  float*  offsLDS = (float*)smem;            // [32][32] f32 overlay (phase A out)
  float4* mwP = (float4*)(smem + 18432);     // [288]
  short4* miP = (short4*)(smem + 23040);     // [288]

  const int tid = threadIdx.x;
  // XCD-aware bijective swizzle: 1152 = 8 XCDs x 144 contiguous strips
  const int blk0 = blockIdx.x;
  const int blk = (blk0 & 7) * 144 + (blk0 >> 3);
  const int b = blk / 288;
  const int r = blk % 288;
  const int ho0 = r / 3;
  const int wo0 = (r % 3) * 32;
  const short* xb = xt + (size_t)b * CHW_;
  const int lane = tid & 63;
  const int wave = tid >> 6;   // 0..1

  // ---- phase A: offset conv for this block's 32 pixels (register MFMA) ----
  {
    const int pA = wave * 16 + (lane & 15);
    const int woA = wo0 + pA;
    const int coff = (lane >> 4) << 3;
    f32x4 oa0 = {0.f, 0.f, 0.f, 0.f}, oa1 = {0.f, 0.f, 0.f, 0.f};
#pragma unroll 4
    for (int s = 0; s < 72; ++s) {
      const int kk = s >> 3;
      const int c0 = (s & 7) << 5;
      const int y = ho0 - 1 + kk / 3;
      const int x = woA - 1 + kk % 3;
      bf16x8 af = {0, 0, 0, 0, 0, 0, 0, 0};
      if ((unsigned)y < 96u && (unsigned)x < 96u)
        af = *(const bf16x8*)(xb + ((y * 96 + x) << 8) + c0 + coff);
      const bf16x8 b0 = *(const bf16x8*)(owfrag + (size_t)s * 1024 + lane * 8);
      const bf16x8 b1 = *(const bf16x8*)(owfrag + (size_t)s * 1024 + 512 + lane * 8);
      oa0 = __builtin_amdgcn_mfma_f32_16x16x32_bf16(af, b0, oa0, 0, 0, 0);
      oa1 = __builtin_amdgcn_mfma_f32_16x16x32_bf16(af, b1, oa1, 0, 0, 0);
    }
    const int r0 = wave * 16 + (lane >> 4) * 4;
    const int cc = lane & 15;
#pragma unroll
    for (int j = 0; j < 4; ++j) {
      offsLDS[(r0 + j) * 32 + cc] = oa0[j];
      offsLDS[(r0 + j) * 32 + 16 + cc] = oa1[j];
    }
  }
  __syncthreads();

  // ---- phase B: sampling metadata: 9 kk x 32 pixels ----
  for (int u = tid; u < 288; u += 128) {
    const int kk = u >> 5;
    const int p = u & 31;
    const int wo = wo0 + p;
    const float dy = offsLDS[p * 32 + 2 * kk] + ob[2 * kk];
    const float dx = offsLDS[p * 32 + 2 * kk + 1] + ob[2 * kk + 1];
    const float py = (float)(ho0 - 1 + kk / 3) + dy;
    const float px = (float)(wo - 1 + kk % 3) + dx;
    const float y0f = floorf(py), x0f = floorf(px);
    const float ty = py - y0f, tx = px - x0f;
    const int y0 = (int)y0f, x0 = (int)x0f;
    const int y1 = y0 + 1, x1 = x0 + 1;
    const float vy0 = ((unsigned)y0 < 96u) ? 1.f : 0.f;
    const float vy1 = ((unsigned)y1 < 96u) ? 1.f : 0.f;
    const float vx0 = ((unsigned)x0 < 96u) ? 1.f : 0.f;
    const float vx1 = ((unsigned)x1 < 96u) ? 1.f : 0.f;
    const float oy = 1.f - ty, ox = 1.f - tx;
    float4 w4;
    w4.x = oy * ox * vy0 * vx0;
    w4.y = oy * tx * vy0 * vx1;
    w4.z = ty * ox * vy1 * vx0;
    w4.w = ty * tx * vy1 * vx1;
    const int cy0 = min(max(y0, 0), 95), cy1 = min(max(y1, 0), 95);
    const int cx0 = min(max(x0, 0), 95), cx1 = min(max(x1, 0), 95);
    mwP[u] = w4;
    miP[u] = make_short4((short)(cy0 * 96 + cx0), (short)(cy0 * 96 + cx1),
                         (short)(cy1 * 96 + cx0), (short)(cy1 * 96 + cx1));
  }
  __syncthreads();

  // ---- phase C: K-step = 64 channels, double-buffered, 1 barrier/step ----
  const int px = tid >> 2;        // 0..31 (staging pixel)
  const int ch0 = (tid & 3) << 4; // 16-channel group base

  f32x4 acc[2][8];
#pragma unroll
  for (int m = 0; m < 2; ++m)
#pragma unroll
    for (int j = 0; j < 8; ++j) acc[m][j] = (f32x4){0.f, 0.f, 0.f, 0.f};

  // staging metadata registers (refreshed when sb % 4 == 0)
  float4 w4 = mwP[px];
  int4 a4;
  {
    const short4 m0 = miP[px];
    a4.x = ((int)m0.x) << 8; a4.y = ((int)m0.y) << 8;
    a4.z = ((int)m0.z) << 8; a4.w = ((int)m0.w) << 8;
  }

  // prologue: stage sb=0 (channels 0..63) into buf0
#pragma unroll
  for (int t = 0; t < 2; ++t) {
    const int cl = ch0 + t * 8;
    const uint4 g0 = *(const uint4*)(xb + a4.x + cl);
    const uint4 g1 = *(const uint4*)(xb + a4.y + cl);
    const uint4 g2 = *(const uint4*)(xb + a4.z + cl);
    const uint4 g3 = *(const uint4*)(xb + a4.w + cl);
    *(bf16x8*)(&vals[px * 72 + cl]) = combine4(g0, g1, g2, g3, w4);
  }
  __syncthreads();

  for (int sb = 0; sb < 36; ++sb) {
    const short* vcur = vals + (sb & 1) * 2304;
    short* vnxt = vals + ((sb & 1) ^ 1) * 2304;
    const int kb0 = 2 * sb;

    // B-fragments: 2 k-subs x 8 n-frags for this wave (L2, 16B/lane)
    bf16x8 bfr[2][8];
    {
      const size_t wb0 = ((size_t)(kb0 * 16 + wave * 8) * 64 + lane) * 8;
      const size_t wb1 = wb0 + (size_t)16 * 64 * 8;
#pragma unroll
      for (int j = 0; j < 8; ++j) bfr[0][j] = *(const bf16x8*)(wfrag + wb0 + (size_t)j * 512);
#pragma unroll
      for (int j = 0; j < 8; ++j) bfr[1][j] = *(const bf16x8*)(wfrag + wb1 + (size_t)j * 512);
    }

    // issue gathers for sb+1 early (covered by the 32 MFMAs below)
    uint4 G[2][4];
    float4 w4n = w4;
    int4 a4n = a4;
    if (sb < 35) {
      const int sbn = sb + 1;
      if ((sbn & 3) == 0) {
        const int kkn = sbn >> 2;
        w4n = mwP[kkn * 32 + px];
        const short4 mn = miP[kkn * 32 + px];
        a4n.x = ((int)mn.x) << 8; a4n.y = ((int)mn.y) << 8;
        a4n.z = ((int)mn.z) << 8; a4n.w = ((int)mn.w) << 8;
      }
      const int cb = ((sbn & 3) << 6) + ch0;
#pragma unroll
      for (int t = 0; t < 2; ++t) {
        const int cl = cb + t * 8;
        G[t][0] = *(const uint4*)(xb + a4n.x + cl);
        G[t][1] = *(const uint4*)(xb + a4n.y + cl);
        G[t][2] = *(const uint4*)(xb + a4n.z + cl);
        G[t][3] = *(const uint4*)(xb + a4n.w + cl);
      }
    }

    // MFMAs on current buffer: 2 k-subs x 2 m-frags x 8 n-frags
#pragma unroll
    for (int ks = 0; ks < 2; ++ks) {
#pragma unroll
      for (int mf = 0; mf < 2; ++mf) {
        const int row = mf * 16 + (lane & 15);
        const bf16x8 af = *(const bf16x8*)(&vcur[row * 72 + ks * 32 + ((lane >> 4) << 3)]);
#pragma unroll
        for (int j = 0; j < 8; ++j)
          acc[mf][j] = __builtin_amdgcn_mfma_f32_16x16x32_bf16(af, bfr[ks][j], acc[mf][j], 0, 0, 0);
      }
    }

    // combine + write next buffer
    if (sb < 35) {
      const int cb = (((sb + 1) & 3) << 6) + ch0;
#pragma unroll
      for (int t = 0; t < 2; ++t) {
        const int cl = cb + t * 8;
        *(bf16x8*)(&vnxt[px * 72 + ((cl) & 63)]) =
            combine4(G[t][0], G[t][1], G[t][2], G[t][3], w4n);
      }
      w4 = w4n; a4 = a4n;
    }
    __syncthreads();
  }

  // ---- epilogue: D regs = 4 consecutive pixels -> float4 stores ----
  const int col = lane & 15;
  const int rg = lane >> 4;
#pragma unroll
  for (int mf = 0; mf < 2; ++mf) {
    const int pix = mf * 16 + rg * 4;
#pragma unroll
    for (int j = 0; j < 8; ++j) {
      const int o = wave * 128 + j * 16 + col;
      const float bv = db[o];
      float4 v;
      v.x = acc[mf][j][0] + bv;
      v.y = acc[mf][j][1] + bv;
      v.z = acc[mf][j][2] + bv;
      v.w = acc[mf][j][3] + bv;
      *(float4*)(out + (size_t)(b * 256 + o) * HW_ + ho0 * 96 + wo0 + pix) = v;
    }
  }
}

extern "C" void kernel_launch(void* const* d_in, const int* in_sizes, int n_in,
                              void* d_out, int out_size, void* d_ws, size_t ws_size,
                              hipStream_t stream) {
  const float* x  = (const float*)d_in[0];
  const float* ow = (const float*)d_in[1];
  const float* ob = (const float*)d_in[2];
  const float* dw = (const float*)d_in[3];
  const float* db = (const float*)d_in[4];
  float* out = (float*)d_out;
  float* ws = (float*)d_ws;

  short* xt     = (short*)ws;                // 9,437,184 bf16 (18.9 MB)
  short* wfrag  = (short*)(ws + 4718592);    //   589,824 bf16
  short* owfrag = wfrag + 589824;            //    73,728 bf16  (~20.2 MB total)

  hipLaunchKernelGGL(k_transpose2, dim3(288, 8, 4), dim3(32, 8, 1), 0, stream, x, xt);
  hipLaunchKernelGGL(k_prep, dim3(2592), dim3(256), 0, stream, dw, ow, wfrag, owfrag);
  hipLaunchKernelGGL(k_deform, dim3(1152), dim3(128), 0, stream,
                     xt, wfrag, owfrag, ob, db, out);
}